// Round 1
// baseline (2028.975 us; speedup 1.0000x reference)
//
#include <hip/hip_runtime.h>

// Problem constants (from reference): N=50000, D=64, R=3, E=800000
#define N_NODES 50000
#define DFEAT   64
#define NREL    3
#define NEDGE   800000
#define OUT_COLS ((NREL + 1) * DFEAT)   // 256 floats per output row

// Kernel 1: initialize output.
// out[i, 0:192] = 0 (accumulators for the 3 relations)
// out[i, 192:256] = x[i, :]
// Vectorized as float4: each row is 64 float4; first 48 zero, last 16 copy x.
__global__ void init_out_kernel(const float4* __restrict__ x4,
                                float4* __restrict__ out4) {
    int j = blockIdx.x * blockDim.x + threadIdx.x;
    if (j >= N_NODES * 64) return;
    int row = j >> 6;      // output row
    int c   = j & 63;      // float4 index within row
    float4 v;
    if (c < 48) {
        v = make_float4(0.f, 0.f, 0.f, 0.f);
    } else {
        v = x4[row * 16 + (c - 48)];
    }
    out4[j] = v;
}

// Kernel 2: scatter-add SpMM for all relations.
// 16 threads per edge; each thread owns one float4 (4 consecutive d) of D=64.
// grid = (E*16/256, R), block = 256.
__global__ void scatter_spmm_kernel(const float* __restrict__ x,
                                    const int* __restrict__ rows,
                                    const int* __restrict__ cols,
                                    const float* __restrict__ vals,
                                    float* __restrict__ out) {
    int idx = blockIdx.x * blockDim.x + threadIdx.x;  // 0 .. E*16-1
    int e   = idx >> 4;
    int sub = idx & 15;
    if (e >= NEDGE) return;
    int r = blockIdx.y;

    long base = (long)r * NEDGE + e;
    int   row = rows[base];
    int   col = cols[base];
    float val = vals[base];

    const float4 xv = *reinterpret_cast<const float4*>(x + (long)col * DFEAT + sub * 4);
    float* o = out + (long)row * OUT_COLS + r * DFEAT + sub * 4;

    atomicAdd(o + 0, val * xv.x);
    atomicAdd(o + 1, val * xv.y);
    atomicAdd(o + 2, val * xv.z);
    atomicAdd(o + 3, val * xv.w);
}

extern "C" void kernel_launch(void* const* d_in, const int* in_sizes, int n_in,
                              void* d_out, int out_size, void* d_ws, size_t ws_size,
                              hipStream_t stream) {
    const float* x        = (const float*)d_in[0];
    const int*   edge_rows = (const int*)d_in[1];
    const int*   edge_cols = (const int*)d_in[2];
    const float* edge_vals = (const float*)d_in[3];
    float* out = (float*)d_out;

    // Init: N*64 float4 elements
    {
        int total = N_NODES * 64;
        int blocks = (total + 255) / 256;
        init_out_kernel<<<blocks, 256, 0, stream>>>(
            (const float4*)x, (float4*)out);
    }

    // Scatter: 16 threads/edge, all relations
    {
        int threads_per_rel = NEDGE * 16;           // 12.8M
        int blocks = (threads_per_rel + 255) / 256; // 50000
        dim3 grid(blocks, NREL);
        scatter_spmm_kernel<<<grid, 256, 0, stream>>>(
            x, edge_rows, edge_cols, edge_vals, out);
    }
}

// Round 2
// 906.538 us; speedup vs baseline: 2.2382x; 2.2382x over previous
//
#include <hip/hip_runtime.h>

// Problem constants: N=50000, D=64, R=3, E=800000
#define N_NODES 50000
#define DFEAT   64
#define NREL    3
#define NEDGE   800000
#define OUT_COLS 256                 // (R+1)*D floats per output row
#define BROWS   128                  // rows per bucket
#define NBUCK   ((N_NODES + BROWS - 1) / BROWS)   // 391
#define TB      (NREL * NBUCK)       // 1173
#define SCAT_BLOCKS 200

// ---------------- bucketed path ----------------

__global__ void zero_counts_kernel(int* __restrict__ counts) {
    int i = blockIdx.x * 256 + threadIdx.x;
    if (i < TB) counts[i] = 0;
}

// grid (128, NREL), block 256. LDS histogram per block, flush with atomics.
__global__ void count_kernel(const int* __restrict__ rows, int* __restrict__ counts) {
    __shared__ int hist[NBUCK];
    int rel = blockIdx.y;
    int tid = threadIdx.x;
    for (int i = tid; i < NBUCK; i += 256) hist[i] = 0;
    __syncthreads();
    const int* rr = rows + rel * NEDGE;
    for (int e = blockIdx.x * 256 + tid; e < NEDGE; e += gridDim.x * 256)
        atomicAdd(&hist[rr[e] >> 7], 1);
    __syncthreads();
    for (int i = tid; i < NBUCK; i += 256)
        if (hist[i]) atomicAdd(&counts[rel * NBUCK + i], hist[i]);
}

// single block of 256. counts[TB] -> offsets[TB+1]; cursor = copy of offsets.
__global__ void scan_kernel(const int* __restrict__ counts,
                            int* __restrict__ offsets,
                            int* __restrict__ cursor) {
    __shared__ int part[256];
    const int PER = (TB + 255) / 256;   // 5
    int t = threadIdx.x;
    int base = t * PER;
    int loc[PER];
    int s = 0;
    for (int k = 0; k < PER; ++k) {
        int idx = base + k;
        int v = (idx < TB) ? counts[idx] : 0;
        loc[k] = s;
        s += v;
    }
    part[t] = s;
    __syncthreads();
    for (int off = 1; off < 256; off <<= 1) {
        int v = 0;
        if (t >= off) v = part[t - off];
        __syncthreads();
        if (t >= off) part[t] += v;
        __syncthreads();
    }
    int excl = (t == 0) ? 0 : part[t - 1];
    for (int k = 0; k < PER; ++k) {
        int idx = base + k;
        if (idx < TB) {
            int v = excl + loc[k];
            offsets[idx] = v;
            cursor[idx]  = v;
        }
    }
    if (t == 255) offsets[TB] = part[255];
}

// grid (SCAT_BLOCKS, NREL), block 256. Two-pass block reservation, then scatter
// packed records {(col<<7)|rowlocal, val_bits} into bucket-contiguous ws.
__global__ void scatter_kernel(const int* __restrict__ rows,
                               const int* __restrict__ cols,
                               const float* __restrict__ vals,
                               int* __restrict__ cursor,
                               uint2* __restrict__ recs) {
    __shared__ int hist[NBUCK];
    __shared__ int basei[NBUCK];
    int rel = blockIdx.y;
    int tid = threadIdx.x;
    for (int i = tid; i < NBUCK; i += 256) hist[i] = 0;
    __syncthreads();
    const int*   rr = rows + rel * NEDGE;
    const int*   cc = cols + rel * NEDGE;
    const float* vv = vals + rel * NEDGE;
    const int chunk = (NEDGE + gridDim.x - 1) / gridDim.x;
    int e0 = blockIdx.x * chunk;
    int e1 = min(e0 + chunk, NEDGE);
    for (int e = e0 + tid; e < e1; e += 256)
        atomicAdd(&hist[rr[e] >> 7], 1);
    __syncthreads();
    for (int i = tid; i < NBUCK; i += 256) {
        int c = hist[i];
        basei[i] = (c > 0) ? atomicAdd(&cursor[rel * NBUCK + i], c) : 0;
        hist[i] = 0;
    }
    __syncthreads();
    for (int e = e0 + tid; e < e1; e += 256) {
        int row = rr[e];
        int bk = row >> 7;
        int pos = basei[bk] + atomicAdd(&hist[bk], 1);
        recs[pos] = make_uint2(((unsigned)cc[e] << 7) | (unsigned)(row & 127),
                               __float_as_uint(vv[e]));
    }
}

// grid TB blocks, block 256 (4 waves). One wave per edge: coalesced 256B gather
// of x[col], LDS atomic accumulate into 128x64 tile, then clean float4 stores.
__global__ void accum_kernel(const float* __restrict__ x,
                             const int* __restrict__ offsets,
                             const uint2* __restrict__ recs,
                             float* __restrict__ out) {
    __shared__ float acc[BROWS * DFEAT];   // 32 KB
    int b    = blockIdx.x;
    int rel  = b / NBUCK;
    int buck = b % NBUCK;
    int tid  = threadIdx.x;
    float4* acc4 = (float4*)acc;
    for (int i = tid; i < BROWS * DFEAT / 4; i += 256)
        acc4[i] = make_float4(0.f, 0.f, 0.f, 0.f);
    __syncthreads();

    int start = offsets[b], end = offsets[b + 1];
    int lane = tid & 63, wave = tid >> 6;

    int j = start + wave;
    for (; j + 4 < end; j += 8) {
        uint2 r0 = recs[j];
        uint2 r1 = recs[j + 4];
        float xv0 = x[(r0.x >> 7) * DFEAT + lane];
        float xv1 = x[(r1.x >> 7) * DFEAT + lane];
        atomicAdd(&acc[(r0.x & 127) * DFEAT + lane], __uint_as_float(r0.y) * xv0);
        atomicAdd(&acc[(r1.x & 127) * DFEAT + lane], __uint_as_float(r1.y) * xv1);
    }
    if (j < end) {
        uint2 r0 = recs[j];
        float xv0 = x[(r0.x >> 7) * DFEAT + lane];
        atomicAdd(&acc[(r0.x & 127) * DFEAT + lane], __uint_as_float(r0.y) * xv0);
    }
    __syncthreads();

    int row0 = buck * BROWS;
    for (int i = tid; i < BROWS * DFEAT / 4; i += 256) {
        int rowl = i >> 4;     // 16 float4 per row
        int c4   = i & 15;
        int row  = row0 + rowl;
        if (row < N_NODES)
            ((float4*)out)[row * (OUT_COLS / 4) + rel * 16 + c4] = acc4[i];
    }
}

// out[:, 192:256] = x
__global__ void copyx_kernel(const float4* __restrict__ x4, float4* __restrict__ out4) {
    int i = blockIdx.x * 256 + threadIdx.x;
    if (i >= N_NODES * 16) return;
    int row = i >> 4, c = i & 15;
    out4[row * (OUT_COLS / 4) + 48 + c] = x4[i];
}

// ---------------- fallback path (no workspace) ----------------

__global__ void init_out_kernel(const float4* __restrict__ x4, float4* __restrict__ out4) {
    int j = blockIdx.x * blockDim.x + threadIdx.x;
    if (j >= N_NODES * 64) return;
    int row = j >> 6, c = j & 63;
    float4 v;
    if (c < 48) v = make_float4(0.f, 0.f, 0.f, 0.f);
    else        v = x4[row * 16 + (c - 48)];
    out4[j] = v;
}

__global__ void scatter_spmm_kernel(const float* __restrict__ x,
                                    const int* __restrict__ rows,
                                    const int* __restrict__ cols,
                                    const float* __restrict__ vals,
                                    float* __restrict__ out) {
    int idx = blockIdx.x * blockDim.x + threadIdx.x;
    int e = idx >> 4, sub = idx & 15;
    if (e >= NEDGE) return;
    int r = blockIdx.y;
    long base = (long)r * NEDGE + e;
    int row = rows[base], col = cols[base];
    float val = vals[base];
    const float4 xv = *reinterpret_cast<const float4*>(x + (long)col * DFEAT + sub * 4);
    float* o = out + (long)row * OUT_COLS + r * DFEAT + sub * 4;
    atomicAdd(o + 0, val * xv.x);
    atomicAdd(o + 1, val * xv.y);
    atomicAdd(o + 2, val * xv.z);
    atomicAdd(o + 3, val * xv.w);
}

// ---------------- launch ----------------

extern "C" void kernel_launch(void* const* d_in, const int* in_sizes, int n_in,
                              void* d_out, int out_size, void* d_ws, size_t ws_size,
                              hipStream_t stream) {
    const float* x         = (const float*)d_in[0];
    const int*   edge_rows = (const int*)d_in[1];
    const int*   edge_cols = (const int*)d_in[2];
    const float* edge_vals = (const float*)d_in[3];
    float* out = (float*)d_out;

    const size_t REC_OFF = 16384;
    const size_t NEED = REC_OFF + (size_t)NREL * NEDGE * sizeof(uint2);  // ~19.3 MB

    if (ws_size >= NEED) {
        int*   counts  = (int*)d_ws;
        int*   offsets = counts + 1280;
        int*   cursor  = offsets + 1280;
        uint2* recs    = (uint2*)((char*)d_ws + REC_OFF);

        zero_counts_kernel<<<(TB + 255) / 256, 256, 0, stream>>>(counts);
        count_kernel<<<dim3(128, NREL), 256, 0, stream>>>(edge_rows, counts);
        scan_kernel<<<1, 256, 0, stream>>>(counts, offsets, cursor);
        scatter_kernel<<<dim3(SCAT_BLOCKS, NREL), 256, 0, stream>>>(
            edge_rows, edge_cols, edge_vals, cursor, recs);
        accum_kernel<<<TB, 256, 0, stream>>>(x, offsets, recs, out);
        copyx_kernel<<<(N_NODES * 16 + 255) / 256, 256, 0, stream>>>(
            (const float4*)x, (float4*)out);
    } else {
        // Fallback: global-atomic scatter (correct, slower)
        {
            int total = N_NODES * 64;
            init_out_kernel<<<(total + 255) / 256, 256, 0, stream>>>(
                (const float4*)x, (float4*)out);
        }
        {
            int threads_per_rel = NEDGE * 16;
            int blocks = (threads_per_rel + 255) / 256;
            dim3 grid(blocks, NREL);
            scatter_spmm_kernel<<<grid, 256, 0, stream>>>(
                x, edge_rows, edge_cols, edge_vals, out);
        }
    }
}